// Round 8
// baseline (126.303 us; speedup 1.0000x reference)
//
#include <hip/hip_runtime.h>
#include <hip/hip_bf16.h>

#define TOKENS 64
#define IN_F 8192
#define OUT_F 8192
#define CB 256

typedef _Float16 half8 __attribute__((ext_vector_type(8)));
typedef float f32x4 __attribute__((ext_vector_type(4)));

// ---------------------------------------------------------------------------
// Kernel 1: xh = FWHT(x * SU) * (1/sqrt(IN_F) * Wscale[0])  -> fp16, stored in
// MFMA-A-FRAGMENT ORDER (k2 A-load = 64 lanes x 16B contiguous):
//   xh_frag[((ks*4 + mt)*64 + quad*16 + l15)*8 + j]
//     = xh_row[mt*16 + l15][ks*32 + quad*8 + j]
// ---------------------------------------------------------------------------
__global__ __launch_bounds__(256) void k_fwht_in(const float* __restrict__ x,
                                                 const float* __restrict__ SU,
                                                 const float* __restrict__ Wscale,
                                                 _Float16* __restrict__ xh_frag)
{
    __shared__ float buf[256 * 33];
    __shared__ _Float16 xrowP[256 * 40];
    const int t    = threadIdx.x;
    const int lane = t & 63;
    const int w    = t >> 6;
    const int row  = blockIdx.x;

    float v[32];
    const float* xr = x + row * IN_F;
#pragma unroll
    for (int r = 0; r < 32; ++r) {
        int e = r * 256 + t;
        v[r] = xr[e] * SU[e];
    }
    // FWHT group A: bits 8..12 (register index)
#pragma unroll
    for (int h = 1; h < 32; h <<= 1) {
#pragma unroll
        for (int r = 0; r < 32; ++r) {
            if ((r & h) == 0) {
                float a = v[r], b = v[r + h];
                v[r] = a + b;
                v[r + h] = a - b;
            }
        }
    }
    // FWHT group B: bits 0..5 (lane bits) via shfl_xor
#pragma unroll
    for (int m = 1; m < 64; m <<= 1) {
        bool upper = (lane & m) != 0;
#pragma unroll
        for (int r = 0; r < 32; ++r) {
            float p = __shfl_xor(v[r], m, 64);
            v[r] = upper ? (p - v[r]) : (v[r] + p);
        }
    }
    // FWHT group C: bits 6..7 (wave bits) via LDS H4
#pragma unroll
    for (int r = 0; r < 32; ++r) buf[t * 33 + r] = v[r];
    __syncthreads();
    {
        float s1 = (w & 1) ? -1.f : 1.f;
        float s2 = (w & 2) ? -1.f : 1.f;
        float s3 = s1 * s2;
#pragma unroll
        for (int r = 0; r < 32; ++r) {
            float a0 = buf[(0 * 64 + lane) * 33 + r];
            float a1 = buf[(1 * 64 + lane) * 33 + r];
            float a2 = buf[(2 * 64 + lane) * 33 + r];
            float a3 = buf[(3 * 64 + lane) * 33 + r];
            v[r] = a0 + s1 * a1 + s2 * a2 + s3 * a3;
        }
    }
    const float scale = 0.011048543456039806f * Wscale[0];  // 1/sqrt(8192)*Wscale
#pragma unroll
    for (int r = 0; r < 32; ++r) {
        int idx = (t & 31) + (r * 8 + (t >> 5)) * 40;   // (c&31) + (c>>5)*40
        xrowP[idx] = (_Float16)(v[r] * scale);
    }
    __syncthreads();
    {
        const int mt  = row >> 4;
        const int l15 = row & 15;
        _Float16* base = xh_frag + ((size_t)(t * 4 + mt) * 64 + l15) * 8;
#pragma unroll
        for (int g = 0; g < 4; ++g) {
            half8 val = *(const half8*)&xrowP[t * 40 + g * 8];
            *(half8*)(base + g * 16 * 8) = val;
        }
    }
}

// ---------------------------------------------------------------------------
// Kernel 2: fused dequant GEMM.  R7 occupancy redesign:
//   R6 was LDS-capped at 2 blocks/CU (73.7 KB) -> 8 waves/CU, LDS-pipe and
//   latency chains poorly overlapped. Now:
//   - Qidxs staged as u16 (values < 256): 16.6 KB
//   - epilogue reduce in 2 rounds (nt 0..1, then 2..3): red 34.8 KB
//   - union(sq, red) + 4 KB codebook ~= 38.8 KB  -> 4 blocks/CU
//   - grid 1024 = 128 n-groups x 8 K-parts (wave K-chunk = 256 = 8 k-steps)
//     so 4 blocks/CU exist device-wide (1024 = 4 x 256 exactly co-resident).
// Wave tile M=64 x N=64, 16 MFMA / k-step, acc 64 VGPR. No barriers in K-loop.
// ---------------------------------------------------------------------------
#define SQ_U16_STRIDE 130   // u16 stride per row (128 + 2 pad)
__global__ __launch_bounds__(256, 4) void k_qgemm(const _Float16* __restrict__ xh_frag,
                                                  const int* __restrict__ Qidxs,
                                                  const float* __restrict__ grid,
                                                  float* __restrict__ y_part)
{
    __shared__ __align__(16) _Float16 glds[CB * 8];       // 4 KB fp16 codebook
    // union: staging/K-loop -> u16 sq[64*130] (16640 B)
    //        epilogue       -> float red[4*64*34] (34816 B)
    __shared__ __align__(16) char uni[4 * 64 * 34 * 4];   // 34816 B
    unsigned short* squ = (unsigned short*)uni;
    float*          red = (float*)uni;

    const int tid = threadIdx.x;
    const int g   = blockIdx.x >> 3; // n-group (128)
    const int p   = blockIdx.x & 7;  // K-part (8)
    const int n0  = g * 64;

    // stage codebook -> LDS fp16
    {
        const float4* gp = (const float4*)grid + tid * 2;
        float4 g0 = gp[0];
        float4 g1 = gp[1];
        _Float16* gl = &glds[tid * 8];
        gl[0] = (_Float16)g0.x; gl[1] = (_Float16)g0.y;
        gl[2] = (_Float16)g0.z; gl[3] = (_Float16)g0.w;
        gl[4] = (_Float16)g1.x; gl[5] = (_Float16)g1.y;
        gl[6] = (_Float16)g1.z; gl[7] = (_Float16)g1.w;
    }
    // Phase A: stage Qidxs slice (rows n0..n0+63, int cols p*128..p*128+127)
    // as u16. 2048 int4 chunks; thread t iter i: idx4 = i*256+t, r=idx4>>5,
    // c4=idx4&31. Coalesced 16B reads; u16 writes ~2-way banks.
#pragma unroll
    for (int i = 0; i < 8; ++i) {
        int idx4 = i * 256 + tid;
        int r  = idx4 >> 5;
        int c4 = idx4 & 31;
        int4 vv = *(const int4*)(Qidxs + (size_t)(n0 + r) * 1024 + p * 128 + c4 * 4);
        unsigned short* dst = &squ[r * SQ_U16_STRIDE + c4 * 4];
        dst[0] = (unsigned short)vv.x; dst[1] = (unsigned short)vv.y;
        dst[2] = (unsigned short)vv.z; dst[3] = (unsigned short)vv.w;
    }
    __syncthreads();

    const int lane = tid & 63;
    const int w    = tid >> 6;        // wave id -> K sub-chunk (256 k = 8 steps)
    const int col  = lane & 15;
    const int quad = lane >> 4;

    // index gather: q(s)[nt] = squ[(nt*16+col)*130 + w*32 + s*4 + quad]
    const int cbase = w * 32 + quad;
#define QGATHER(dst4, s)                                                   \
    {                                                                      \
        int cc = cbase + (s) * 4;                                          \
        dst4.x = (int)squ[(0 * 16 + col) * SQ_U16_STRIDE + cc];            \
        dst4.y = (int)squ[(1 * 16 + col) * SQ_U16_STRIDE + cc];            \
        dst4.z = (int)squ[(2 * 16 + col) * SQ_U16_STRIDE + cc];            \
        dst4.w = (int)squ[(3 * 16 + col) * SQ_U16_STRIDE + cc];            \
    }

    // A fragment base: global kstep Ks = p*32 + w*8 + s; frag (s,mt) at +(s*4+mt)*512
    const _Float16* abase = xh_frag + ((size_t)(p * 32 + w * 8) * 4 * 64 + lane) * 8;

    f32x4 acc[4][4] = {};   // [nt][mt]

    // ---- pipeline prologue: b_c = b(0), qv1 = q(1), qv2 = q(2) ----
    int4 qv1, qv2;
    half8 b_c[4];
    {
        int4 qv0;
        QGATHER(qv0, 0);
        QGATHER(qv1, 1);
        QGATHER(qv2, 2);
        b_c[0] = *(const half8*)&glds[qv0.x * 8];
        b_c[1] = *(const half8*)&glds[qv0.y * 8];
        b_c[2] = *(const half8*)&glds[qv0.z * 8];
        b_c[3] = *(const half8*)&glds[qv0.w * 8];
    }
    half8 a_c[4], a_n[4];
#pragma unroll
    for (int mt = 0; mt < 4; ++mt) {
        a_c[mt] = *(const half8*)(abase + (size_t)(0 * 4 + mt) * 512);
        a_n[mt] = *(const half8*)(abase + (size_t)(1 * 4 + mt) * 512);
    }

#pragma unroll
    for (int s = 0; s < 8; ++s) {
        const int s3 = (s + 3 < 8 ? s + 3 : 7);
        const int s2 = (s + 2 < 8 ? s + 2 : 7);
        int4 qn;
        QGATHER(qn, s3);                                 // q(s+3), LDS u16
        half8 b_n[4], a_nn[4];
        b_n[0] = *(const half8*)&glds[qv1.x * 8];        // b(s+1)
        b_n[1] = *(const half8*)&glds[qv1.y * 8];
        b_n[2] = *(const half8*)&glds[qv1.z * 8];
        b_n[3] = *(const half8*)&glds[qv1.w * 8];
#pragma unroll
        for (int mt = 0; mt < 4; ++mt)
            a_nn[mt] = *(const half8*)(abase + (size_t)(s2 * 4 + mt) * 512); // a(s+2)
#pragma unroll
        for (int nt = 0; nt < 4; ++nt)
#pragma unroll
            for (int mt = 0; mt < 4; ++mt)
                acc[nt][mt] = __builtin_amdgcn_mfma_f32_16x16x32_f16(
                    a_c[mt], b_c[nt], acc[nt][mt], 0, 0, 0);
#pragma unroll
        for (int nt = 0; nt < 4; ++nt) b_c[nt] = b_n[nt];
        qv1 = qv2; qv2 = qn;
#pragma unroll
        for (int mt = 0; mt < 4; ++mt) { a_c[mt] = a_n[mt]; a_n[mt] = a_nn[mt]; }
    }

    // ---- epilogue: 2-round 4-wave reduce (red aliases squ) ----
    // C/D layout: token r = mt*16 + quad*4 + i, feature c = nt*16 + col
    float* yp = y_part + (size_t)p * TOKENS * OUT_F;
#pragma unroll
    for (int h = 0; h < 2; ++h) {
        __syncthreads();   // h=0: all waves out of K-loop; h=1: round-0 reads done
#pragma unroll
        for (int nt2 = 0; nt2 < 2; ++nt2) {
            int nt = h * 2 + nt2;
#pragma unroll
            for (int mt = 0; mt < 4; ++mt)
#pragma unroll
                for (int i = 0; i < 4; ++i) {
                    int r = mt * 16 + quad * 4 + i;
                    red[(w * 64 + r) * 34 + nt2 * 16 + col] = acc[nt][mt][i];
                }
        }
        __syncthreads();
#pragma unroll
        for (int j = 0; j < 8; ++j) {
            int idx = j * 256 + tid;        // [0, 2048): 64 tokens x 32 cc
            int rr = idx >> 5, cc = idx & 31;
            float s = (red[(0 * 64 + rr) * 34 + cc] + red[(1 * 64 + rr) * 34 + cc])
                    + (red[(2 * 64 + rr) * 34 + cc] + red[(3 * 64 + rr) * 34 + cc]);
            yp[(size_t)rr * OUT_F + n0 + h * 32 + cc] = s;
        }
    }
#undef QGATHER
}

// ---------------------------------------------------------------------------
// Kernel 3: fold 8 K-part partials, FWHT, * 1/sqrt(OUT_F) * SV + bias
// ---------------------------------------------------------------------------
__global__ __launch_bounds__(256) void k_fwht_out(const float* __restrict__ y_part,
                                                  const float* __restrict__ SV,
                                                  const float* __restrict__ bias,
                                                  float* __restrict__ out)
{
    __shared__ float buf[256 * 33];
    const int t    = threadIdx.x;
    const int lane = t & 63;
    const int w    = t >> 6;
    const int row  = blockIdx.x;

    const float* y0 = y_part + (size_t)row * OUT_F;
    const size_t ps = (size_t)TOKENS * OUT_F;

    float v[32];
#pragma unroll
    for (int r = 0; r < 32; ++r) {
        int e = r * 256 + t;
        float s = 0.f;
#pragma unroll
        for (int q = 0; q < 8; ++q) s += y0[e + q * ps];
        v[r] = s;
    }
#pragma unroll
    for (int h = 1; h < 32; h <<= 1) {
#pragma unroll
        for (int r = 0; r < 32; ++r) {
            if ((r & h) == 0) {
                float a = v[r], b = v[r + h];
                v[r] = a + b;
                v[r + h] = a - b;
            }
        }
    }
#pragma unroll
    for (int m = 1; m < 64; m <<= 1) {
        bool upper = (lane & m) != 0;
#pragma unroll
        for (int r = 0; r < 32; ++r) {
            float p = __shfl_xor(v[r], m, 64);
            v[r] = upper ? (p - v[r]) : (v[r] + p);
        }
    }
#pragma unroll
    for (int r = 0; r < 32; ++r) buf[t * 33 + r] = v[r];
    __syncthreads();
    {
        float s1 = (w & 1) ? -1.f : 1.f;
        float s2 = (w & 2) ? -1.f : 1.f;
        float s3 = s1 * s2;
#pragma unroll
        for (int r = 0; r < 32; ++r) {
            float a0 = buf[(0 * 64 + lane) * 33 + r];
            float a1 = buf[(1 * 64 + lane) * 33 + r];
            float a2 = buf[(2 * 64 + lane) * 33 + r];
            float a3 = buf[(3 * 64 + lane) * 33 + r];
            v[r] = a0 + s1 * a1 + s2 * a2 + s3 * a3;
        }
    }
    const float scale = 0.011048543456039806f;  // 1/sqrt(8192)
    float* oo = out + (size_t)row * OUT_F;
#pragma unroll
    for (int r = 0; r < 32; ++r) {
        int e = r * 256 + t;
        oo[e] = v[r] * scale * SV[e] + bias[e];
    }
}

extern "C" void kernel_launch(void* const* d_in, const int* in_sizes, int n_in,
                              void* d_out, int out_size, void* d_ws, size_t ws_size,
                              hipStream_t stream) {
    const float* x      = (const float*)d_in[0];
    const float* SU     = (const float*)d_in[1];
    const float* SV     = (const float*)d_in[2];
    const float* grid   = (const float*)d_in[3];
    const float* Wscale = (const float*)d_in[4];
    const float* bias   = (const float*)d_in[5];
    const int*   Qidxs  = (const int*)d_in[6];
    float* out = (float*)d_out;

    // ws layout: xh_frag 1 MB | y_part 8 x 2 MB = 16 MB
    _Float16* xh_frag = (_Float16*)d_ws;
    float*    y_part  = (float*)((char*)d_ws + ((size_t)1 << 20));

    k_fwht_in<<<TOKENS, 256, 0, stream>>>(x, SU, Wscale, xh_frag);
    k_qgemm<<<1024, 256, 0, stream>>>(xh_frag, Qidxs, grid, y_part);
    k_fwht_out<<<TOKENS, 256, 0, stream>>>(y_part, SV, bias, out);
}

// Round 9
// 112.980 us; speedup vs baseline: 1.1179x; 1.1179x over previous
//
#include <hip/hip_runtime.h>
#include <hip/hip_bf16.h>

#define TOKENS 64
#define IN_F 8192
#define OUT_F 8192
#define CB 256

typedef _Float16 half8 __attribute__((ext_vector_type(8)));
typedef float f32x4 __attribute__((ext_vector_type(4)));

// ---------------------------------------------------------------------------
// Kernel 1: xh = FWHT(x * SU) * (1/sqrt(IN_F) * Wscale[0])  -> fp16, stored in
// MFMA-A-FRAGMENT ORDER (k2 A-load = 64 lanes x 16B contiguous):
//   xh_frag[((ks*4 + mt)*64 + quad*16 + l15)*8 + j]
//     = xh_row[mt*16 + l15][ks*32 + quad*8 + j]
// ---------------------------------------------------------------------------
__global__ __launch_bounds__(256) void k_fwht_in(const float* __restrict__ x,
                                                 const float* __restrict__ SU,
                                                 const float* __restrict__ Wscale,
                                                 _Float16* __restrict__ xh_frag)
{
    __shared__ float buf[256 * 33];
    __shared__ _Float16 xrowP[256 * 40];
    const int t    = threadIdx.x;
    const int lane = t & 63;
    const int w    = t >> 6;
    const int row  = blockIdx.x;

    float v[32];
    const float* xr = x + row * IN_F;
#pragma unroll
    for (int r = 0; r < 32; ++r) {
        int e = r * 256 + t;
        v[r] = xr[e] * SU[e];
    }
    // FWHT group A: bits 8..12 (register index)
#pragma unroll
    for (int h = 1; h < 32; h <<= 1) {
#pragma unroll
        for (int r = 0; r < 32; ++r) {
            if ((r & h) == 0) {
                float a = v[r], b = v[r + h];
                v[r] = a + b;
                v[r + h] = a - b;
            }
        }
    }
    // FWHT group B: bits 0..5 (lane bits) via shfl_xor
#pragma unroll
    for (int m = 1; m < 64; m <<= 1) {
        bool upper = (lane & m) != 0;
#pragma unroll
        for (int r = 0; r < 32; ++r) {
            float p = __shfl_xor(v[r], m, 64);
            v[r] = upper ? (p - v[r]) : (v[r] + p);
        }
    }
    // FWHT group C: bits 6..7 (wave bits) via LDS H4
#pragma unroll
    for (int r = 0; r < 32; ++r) buf[t * 33 + r] = v[r];
    __syncthreads();
    {
        float s1 = (w & 1) ? -1.f : 1.f;
        float s2 = (w & 2) ? -1.f : 1.f;
        float s3 = s1 * s2;
#pragma unroll
        for (int r = 0; r < 32; ++r) {
            float a0 = buf[(0 * 64 + lane) * 33 + r];
            float a1 = buf[(1 * 64 + lane) * 33 + r];
            float a2 = buf[(2 * 64 + lane) * 33 + r];
            float a3 = buf[(3 * 64 + lane) * 33 + r];
            v[r] = a0 + s1 * a1 + s2 * a2 + s3 * a3;
        }
    }
    const float scale = 0.011048543456039806f * Wscale[0];  // 1/sqrt(8192)*Wscale
#pragma unroll
    for (int r = 0; r < 32; ++r) {
        int idx = (t & 31) + (r * 8 + (t >> 5)) * 40;   // (c&31) + (c>>5)*40
        xrowP[idx] = (_Float16)(v[r] * scale);
    }
    __syncthreads();
    {
        const int mt  = row >> 4;
        const int l15 = row & 15;
        _Float16* base = xh_frag + ((size_t)(t * 4 + mt) * 64 + l15) * 8;
#pragma unroll
        for (int g = 0; g < 4; ++g) {
            half8 val = *(const half8*)&xrowP[t * 40 + g * 8];
            *(half8*)(base + g * 16 * 8) = val;
        }
    }
}

// ---------------------------------------------------------------------------
// Kernel 2: fused dequant GEMM with in-kernel Qidxs staging. R8 = exact R6
// revert (best measured point, 113.0 µs wall).
// R7 POST-MORTEM (8 K-parts, 4 blocks/CU, u16 staging): REGRESSED to 126.3 —
// k2 is NOT occupancy-bound; the extra epilogues (2x blocks), doubled y_part
// traffic, and 8-step K-loop with 3-deep prefetch clamps cost more than the
// added wave-overlap gained. k2's ~18 µs ~= partially-overlapped
// {LDS gather ~6.4 µs (131K wave-gathers x ~30cyc / 256 CU, algorithm-
// invariant), HBM ~6.4 µs (~40 MB), MFMA ~4 µs} — near structural floor.
//
// Grid: 512 blocks = 128 n-groups x 4 K-parts; 4 waves split the K-part.
// Wave tile M=64 x N=64, 16x16x32 f16 MFMA, acc 64 VGPR.
// Phase A: stage 64-row x 256-int Qidxs slice into LDS (wave-coalesced 1KB
//   row reads; stride 261 -> ~2-way gather conflicts).
// Phase B: 16-step K-loop; q = 4x ds_read_b32, B = LDS codebook 16B gather,
//   A = contiguous 1KB global fragment loads. No barriers in the K-loop.
// Epilogue: red ALIASES sq's LDS -> 73.7 KB total, 2 blocks/CU.
// ---------------------------------------------------------------------------
#define SQ_STRIDE 261
__global__ __launch_bounds__(256, 2) void k_qgemm(const _Float16* __restrict__ xh_frag,
                                                  const int* __restrict__ Qidxs,
                                                  const float* __restrict__ grid,
                                                  float* __restrict__ y_part)
{
    __shared__ __align__(16) _Float16 glds[CB * 8];       // 4 KB fp16 codebook
    // union region: phase A/B -> int sq[64*261] (66.8 KB);
    //               epilogue  -> float red[4*64*68] (69.6 KB)
    __shared__ __align__(16) char uni[4 * 64 * 68 * 4];   // 69632 B
    int*   sq  = (int*)uni;
    float* red = (float*)uni;

    const int tid = threadIdx.x;
    const int g   = blockIdx.x >> 2; // n-group (128)
    const int p   = blockIdx.x & 3;  // K-part (4)
    const int n0  = g * 64;

    // stage codebook -> LDS fp16
    {
        const float4* gp = (const float4*)grid + tid * 2;
        float4 g0 = gp[0];
        float4 g1 = gp[1];
        _Float16* gl = &glds[tid * 8];
        gl[0] = (_Float16)g0.x; gl[1] = (_Float16)g0.y;
        gl[2] = (_Float16)g0.z; gl[3] = (_Float16)g0.w;
        gl[4] = (_Float16)g1.x; gl[5] = (_Float16)g1.y;
        gl[6] = (_Float16)g1.z; gl[7] = (_Float16)g1.w;
    }
    // Phase A: stage Qidxs slice (rows n0..n0+63, int cols p*256..p*256+255)
#pragma unroll
    for (int i = 0; i < 16; ++i) {
        int idx4 = i * 256 + tid;
        int r  = idx4 >> 6;
        int c4 = idx4 & 63;
        int4 vv = *(const int4*)(Qidxs + (size_t)(n0 + r) * 1024 + p * 256 + c4 * 4);
        int* dst = &sq[r * SQ_STRIDE + c4 * 4];
        dst[0] = vv.x; dst[1] = vv.y; dst[2] = vv.z; dst[3] = vv.w;
    }
    __syncthreads();

    const int lane = tid & 63;
    const int w    = tid >> 6;        // wave id -> K sub-chunk
    const int col  = lane & 15;
    const int quad = lane >> 4;

    // index gather from sq: q(s)[nt] = sq[(nt*16+col)*261 + w*64 + s*4 + quad]
    const int cbase = w * 64 + quad;
#define QGATHER(dst4, s)                                              \
    {                                                                 \
        int cc = cbase + (s) * 4;                                     \
        dst4.x = sq[(0 * 16 + col) * SQ_STRIDE + cc];                 \
        dst4.y = sq[(1 * 16 + col) * SQ_STRIDE + cc];                 \
        dst4.z = sq[(2 * 16 + col) * SQ_STRIDE + cc];                 \
        dst4.w = sq[(3 * 16 + col) * SQ_STRIDE + cc];                 \
    }

    // A fragment base: global kstep Ks = p*64 + w*16 + s; frag (s,mt) at +(s*4+mt)*512
    const _Float16* abase = xh_frag + ((size_t)(p * 64 + w * 16) * 4 * 64 + lane) * 8;

    f32x4 acc[4][4] = {};   // [nt][mt]

    // ---- pipeline prologue: b_c = b(0), qv1 = q(1), qv2 = q(2) ----
    int4 qv1, qv2;
    half8 b_c[4];
    {
        int4 qv0;
        QGATHER(qv0, 0);
        QGATHER(qv1, 1);
        QGATHER(qv2, 2);
        b_c[0] = *(const half8*)&glds[qv0.x * 8];
        b_c[1] = *(const half8*)&glds[qv0.y * 8];
        b_c[2] = *(const half8*)&glds[qv0.z * 8];
        b_c[3] = *(const half8*)&glds[qv0.w * 8];
    }
    half8 a_c[4], a_n[4];
#pragma unroll
    for (int mt = 0; mt < 4; ++mt) {
        a_c[mt] = *(const half8*)(abase + (size_t)(0 * 4 + mt) * 512);
        a_n[mt] = *(const half8*)(abase + (size_t)(1 * 4 + mt) * 512);
    }

#pragma unroll 4
    for (int s = 0; s < 16; ++s) {
        const int s3 = (s + 3 < 16 ? s + 3 : 15);
        const int s2 = (s + 2 < 16 ? s + 2 : 15);
        int4 qn;
        QGATHER(qn, s3);                                 // q(s+3), LDS
        half8 b_n[4], a_nn[4];
        b_n[0] = *(const half8*)&glds[qv1.x * 8];        // b(s+1)
        b_n[1] = *(const half8*)&glds[qv1.y * 8];
        b_n[2] = *(const half8*)&glds[qv1.z * 8];
        b_n[3] = *(const half8*)&glds[qv1.w * 8];
#pragma unroll
        for (int mt = 0; mt < 4; ++mt)
            a_nn[mt] = *(const half8*)(abase + (size_t)(s2 * 4 + mt) * 512); // a(s+2)
#pragma unroll
        for (int nt = 0; nt < 4; ++nt)
#pragma unroll
            for (int mt = 0; mt < 4; ++mt)
                acc[nt][mt] = __builtin_amdgcn_mfma_f32_16x16x32_f16(
                    a_c[mt], b_c[nt], acc[nt][mt], 0, 0, 0);
#pragma unroll
        for (int nt = 0; nt < 4; ++nt) b_c[nt] = b_n[nt];
        qv1 = qv2; qv2 = qn;
#pragma unroll
        for (int mt = 0; mt < 4; ++mt) { a_c[mt] = a_n[mt]; a_n[mt] = a_nn[mt]; }
    }

    // ---- epilogue: red aliases sq; barrier ensures all waves left the K-loop
    __syncthreads();
    // C/D layout: token r = mt*16 + quad*4 + i, feature c = nt*16 + col
#pragma unroll
    for (int nt = 0; nt < 4; ++nt)
#pragma unroll
        for (int mt = 0; mt < 4; ++mt)
#pragma unroll
            for (int i = 0; i < 4; ++i) {
                int r = mt * 16 + quad * 4 + i;
                int c = nt * 16 + col;
                red[(w * 64 + r) * 68 + c] = acc[nt][mt][i];
            }
    __syncthreads();
    float* yp = y_part + (size_t)p * TOKENS * OUT_F;
#pragma unroll
    for (int j = 0; j < 16; ++j) {
        int idx = j * 256 + tid;
        int rr = idx >> 6, cc = idx & 63;
        float s = (red[(0 * 64 + rr) * 68 + cc] + red[(1 * 64 + rr) * 68 + cc])
                + (red[(2 * 64 + rr) * 68 + cc] + red[(3 * 64 + rr) * 68 + cc]);
        yp[(size_t)rr * OUT_F + n0 + cc] = s;
    }
#undef QGATHER
}

// ---------------------------------------------------------------------------
// Kernel 3: fold 4 K-part partials, FWHT, * 1/sqrt(OUT_F) * SV + bias
// ---------------------------------------------------------------------------
__global__ __launch_bounds__(256) void k_fwht_out(const float* __restrict__ y_part,
                                                  const float* __restrict__ SV,
                                                  const float* __restrict__ bias,
                                                  float* __restrict__ out)
{
    __shared__ float buf[256 * 33];
    const int t    = threadIdx.x;
    const int lane = t & 63;
    const int w    = t >> 6;
    const int row  = blockIdx.x;

    const float* y0 = y_part + (size_t)row * OUT_F;
    const size_t ps = (size_t)TOKENS * OUT_F;

    float v[32];
#pragma unroll
    for (int r = 0; r < 32; ++r) {
        int e = r * 256 + t;
        v[r] = (y0[e] + y0[e + ps]) + (y0[e + 2 * ps] + y0[e + 3 * ps]);
    }
#pragma unroll
    for (int h = 1; h < 32; h <<= 1) {
#pragma unroll
        for (int r = 0; r < 32; ++r) {
            if ((r & h) == 0) {
                float a = v[r], b = v[r + h];
                v[r] = a + b;
                v[r + h] = a - b;
            }
        }
    }
#pragma unroll
    for (int m = 1; m < 64; m <<= 1) {
        bool upper = (lane & m) != 0;
#pragma unroll
        for (int r = 0; r < 32; ++r) {
            float p = __shfl_xor(v[r], m, 64);
            v[r] = upper ? (p - v[r]) : (v[r] + p);
        }
    }
#pragma unroll
    for (int r = 0; r < 32; ++r) buf[t * 33 + r] = v[r];
    __syncthreads();
    {
        float s1 = (w & 1) ? -1.f : 1.f;
        float s2 = (w & 2) ? -1.f : 1.f;
        float s3 = s1 * s2;
#pragma unroll
        for (int r = 0; r < 32; ++r) {
            float a0 = buf[(0 * 64 + lane) * 33 + r];
            float a1 = buf[(1 * 64 + lane) * 33 + r];
            float a2 = buf[(2 * 64 + lane) * 33 + r];
            float a3 = buf[(3 * 64 + lane) * 33 + r];
            v[r] = a0 + s1 * a1 + s2 * a2 + s3 * a3;
        }
    }
    const float scale = 0.011048543456039806f;  // 1/sqrt(8192)
    float* oo = out + (size_t)row * OUT_F;
#pragma unroll
    for (int r = 0; r < 32; ++r) {
        int e = r * 256 + t;
        oo[e] = v[r] * scale * SV[e] + bias[e];
    }
}

extern "C" void kernel_launch(void* const* d_in, const int* in_sizes, int n_in,
                              void* d_out, int out_size, void* d_ws, size_t ws_size,
                              hipStream_t stream) {
    const float* x      = (const float*)d_in[0];
    const float* SU     = (const float*)d_in[1];
    const float* SV     = (const float*)d_in[2];
    const float* grid   = (const float*)d_in[3];
    const float* Wscale = (const float*)d_in[4];
    const float* bias   = (const float*)d_in[5];
    const int*   Qidxs  = (const int*)d_in[6];
    float* out = (float*)d_out;

    // ws layout: xh_frag 1 MB | y_part 8 MB
    _Float16* xh_frag = (_Float16*)d_ws;
    float*    y_part  = (float*)((char*)d_ws + ((size_t)1 << 20));

    k_fwht_in<<<TOKENS, 256, 0, stream>>>(x, SU, Wscale, xh_frag);
    k_qgemm<<<512, 256, 0, stream>>>(xh_frag, Qidxs, grid, y_part);
    k_fwht_out<<<TOKENS, 256, 0, stream>>>(y_part, SV, bias, out);
}